// Round 1
// baseline (213.966 us; speedup 1.0000x reference)
//
#include <hip/hip_runtime.h>

typedef _Float16 f16;
typedef _Float16 f16x8 __attribute__((ext_vector_type(8)));
typedef float f32x4 __attribute__((ext_vector_type(4)));

#define IN_DIM  8192
#define OUT_DIM 8192
#define BATCH   256
#define BK      32
#define BN      128
#define NSPLIT  4
#define KSPL    (IN_DIM / NSPLIT)   /* 2048 per split */
#define NSTEP   (KSPL / BK)         /* 64 K-steps */

__device__ __forceinline__ float softplus_f(float r) {
    // rho ~ N(-3, 0.1): exp can't overflow; fast hw exp/log is ~1e-5 rel,
    // far below the f16 rounding we apply afterwards.
    return __logf(1.0f + __expf(r));
}

// Issue next K-step's global loads into a named register set (10 x f32x4).
#define ISSUE(S, A0a,A0b,A1a,A1b,M0,M1,R0,R1,E0,E1) do {                     \
    const int o_ = (S) * BK;                                                 \
    A0a = *(const f32x4*)(xp0 + o_);   A0b = *(const f32x4*)(xp0 + o_ + 4);  \
    A1a = *(const f32x4*)(xp1 + o_);   A1b = *(const f32x4*)(xp1 + o_ + 4);  \
    M0  = *(const f32x4*)(mup + o_);   M1  = *(const f32x4*)(mup + o_ + 4);  \
    R0  = *(const f32x4*)(rhp + o_);   R1  = *(const f32x4*)(rhp + o_ + 4);  \
    E0  = *(const f32x4*)(epp + o_);   E1  = *(const f32x4*)(epp + o_ + 4);  \
} while (0)

// Convert + softplus-combine and ds_write_b128 into LDS buffer BUF.
#define COMMIT(BUF, A0a,A0b,A1a,A1b,M0,M1,R0,R1,E0,E1) do {                  \
    f16x8 av0_, av1_, wv_;                                                   \
    _Pragma("unroll")                                                        \
    for (int q_ = 0; q_ < 4; ++q_) {                                         \
        av0_[q_]   = (f16)A0a[q_];  av0_[4+q_] = (f16)A0b[q_];               \
        av1_[q_]   = (f16)A1a[q_];  av1_[4+q_] = (f16)A1b[q_];               \
        wv_[q_]   = (f16)(M0[q_] + softplus_f(R0[q_]) * E0[q_]);             \
        wv_[4+q_] = (f16)(M1[q_] + softplus_f(R1[q_]) * E1[q_]);             \
    }                                                                        \
    *(f16x8*)&sm[BUF][a_st0] = av0_;                                         \
    *(f16x8*)&sm[BUF][a_st1] = av1_;                                         \
    *(f16x8*)&sm[BUF][b_st]  = wv_;                                          \
} while (0)

// One K-step of MFMA: 4x4 fragments of 16x16x32 f16 per wave (64x64 tile).
#define MSTEP(BUF) do {                                                      \
    f16x8 af_[4], bf_[4];                                                    \
    const int sl_ = lane >> 4;                                               \
    _Pragma("unroll")                                                        \
    for (int i_ = 0; i_ < 4; ++i_) {                                         \
        const int ar_ = wm * 64 + i_ * 16 + (lane & 15);                     \
        af_[i_] = *(const f16x8*)&sm[BUF][ar_ * BK + ((sl_ ^ (ar_ & 3)) << 3)]; \
        const int br_ = wn * 64 + i_ * 16 + (lane & 15);                     \
        bf_[i_] = *(const f16x8*)&sm[BUF][BATCH * BK + br_ * BK + ((sl_ ^ (br_ & 3)) << 3)]; \
    }                                                                        \
    _Pragma("unroll")                                                        \
    for (int i_ = 0; i_ < 4; ++i_)                                           \
        _Pragma("unroll")                                                    \
        for (int j_ = 0; j_ < 4; ++j_)                                       \
            acc[i_][j_] = __builtin_amdgcn_mfma_f32_16x16x32_f16(            \
                af_[i_], bf_[j_], acc[i_][j_], 0, 0, 0);                     \
} while (0)

// Barrier that drains only LDS ops; global loads stay in flight across it.
#define BARRIER() do {                                                       \
    asm volatile("s_waitcnt lgkmcnt(0)" ::: "memory");                       \
    __builtin_amdgcn_s_barrier();                                            \
} while (0)

__global__ __launch_bounds__(512, 2)
void vl_main(const float* __restrict__ x,
             const float* __restrict__ muw,
             const float* __restrict__ rhow,
             const float* __restrict__ epsw,
             const float* __restrict__ mub,
             const float* __restrict__ rhob,
             const float* __restrict__ epsb,
             float* __restrict__ out)
{
    // A tile [256][32] f16 + B tile [128][32] f16, double-buffered = 48 KiB
    __shared__ __align__(16) f16 sm[2][BATCH * BK + BN * BK];

    const int t    = threadIdx.x;
    const int lane = t & 63;
    const int wid  = t >> 6;     // 0..7
    const int wm   = wid >> 1;   // 0..3 : m0 = wm*64
    const int wn   = wid & 1;    // 0..1 : n0 = wn*64

    // XCD-aware mapping: XCD = bx%8 gets one k-split (its 2 MiB x-chunk
    // stays L2-resident) and 32 n-blocks.
    const int bx = blockIdx.x;
    const int x7 = bx & 7;
    const int sk = x7 >> 1;                      // 0..3 k-split
    const int nb = (x7 & 1) * 32 + (bx >> 3);    // 0..63 n-block
    const int k_base = sk * KSPL;
    const int n_base = nb * BN;

    // staging assignment: thread -> (row = t>>2, 16B slot = t&3)
    const int slot = t & 3;
    const int row  = t >> 2;     // 0..127

    const float* xp0 = x + (size_t)row * IN_DIM + k_base + slot * 8;
    const float* xp1 = xp0 + (size_t)128 * IN_DIM;
    const size_t woff = (size_t)(n_base + row) * IN_DIM + k_base + slot * 8;
    const float* mup = muw  + woff;
    const float* rhp = rhow + woff;
    const float* epp = epsw + woff;

    // XOR-swizzled LDS half-indices (slot ^= row&3 kills the stride-64B
    // bank conflict on ds_read_b128; write side uses the same involution).
    const int a_sw  = (slot ^ (row & 3)) << 3;
    const int a_st0 = row * BK + a_sw;
    const int a_st1 = (row + 128) * BK + a_sw;   // (row+128)&3 == row&3
    const int b_st  = BATCH * BK + row * BK + a_sw;

    f32x4 acc[4][4];
#pragma unroll
    for (int i = 0; i < 4; ++i)
#pragma unroll
        for (int j = 0; j < 4; ++j)
            acc[i][j] = (f32x4){0.f, 0.f, 0.f, 0.f};

    // Two named register sets (static indexing -> no scratch, rule #20).
    f32x4 A0a0,A0b0,A1a0,A1b0,M00,M10,R00,R10,E00,E10;  // set0
    f32x4 A0a1,A0b1,A1a1,A1b1,M01,M11,R01,R11,E01,E11;  // set1

    // Prologue: set0 <- k0, set1 <- k1, commit k0 into buf0.
    ISSUE(0, A0a0,A0b0,A1a0,A1b0,M00,M10,R00,R10,E00,E10);
    ISSUE(1, A0a1,A0b1,A1a1,A1b1,M01,M11,R01,R11,E01,E11);
    COMMIT(0, A0a0,A0b0,A1a0,A1b0,M00,M10,R00,R10,E00,E10);
    BARRIER();

    for (int s = 0; s < NSTEP; s += 2) {
        // even step: compute buf0 (k=s), commit set1 (k=s+1) -> buf1,
        // prefetch k=s+2 into set0.
        if (s + 2 < NSTEP) ISSUE(s + 2, A0a0,A0b0,A1a0,A1b0,M00,M10,R00,R10,E00,E10);
        MSTEP(0);
        COMMIT(1, A0a1,A0b1,A1a1,A1b1,M01,M11,R01,R11,E01,E11);
        BARRIER();
        // odd step: compute buf1 (k=s+1), commit set0 (k=s+2) -> buf0,
        // prefetch k=s+3 into set1.
        if (s + 3 < NSTEP) ISSUE(s + 3, A0a1,A0b1,A1a1,A1b1,M01,M11,R01,R11,E01,E11);
        MSTEP(1);
        if (s + 2 < NSTEP) COMMIT(0, A0a0,A0b0,A1a0,A1b0,M00,M10,R00,R10,E00,E10);
        BARRIER();
    }

    // Epilogue: bias (only k-split 0 adds it), then one f32 atomicAdd per
    // output element per split (d_out zeroed by hipMemsetAsync in launch).
    float bias[4] = {0.f, 0.f, 0.f, 0.f};
    if (sk == 0) {
#pragma unroll
        for (int j = 0; j < 4; ++j) {
            const int c = n_base + wn * 64 + j * 16 + (lane & 15);
            bias[j] = mub[c] + softplus_f(rhob[c]) * epsb[c];
        }
    }
#pragma unroll
    for (int i = 0; i < 4; ++i) {
        const int r = wm * 64 + i * 16 + ((lane >> 4) << 2);
#pragma unroll
        for (int j = 0; j < 4; ++j) {
            const int c = n_base + wn * 64 + j * 16 + (lane & 15);
            float* po = out + (size_t)r * OUT_DIM + c;
#pragma unroll
            for (int q = 0; q < 4; ++q)
                atomicAdd(po + (size_t)q * OUT_DIM, acc[i][j][q] + bias[j]);
        }
    }
}

extern "C" void kernel_launch(void* const* d_in, const int* in_sizes, int n_in,
                              void* d_out, int out_size, void* d_ws, size_t ws_size,
                              hipStream_t stream) {
    (void)in_sizes; (void)n_in; (void)d_ws; (void)ws_size;
    const float* x    = (const float*)d_in[0];
    const float* muw  = (const float*)d_in[1];
    const float* rhow = (const float*)d_in[2];
    const float* mub  = (const float*)d_in[3];
    const float* rhob = (const float*)d_in[4];
    const float* epsw = (const float*)d_in[5];
    const float* epsb = (const float*)d_in[6];
    float* out = (float*)d_out;

    hipMemsetAsync(out, 0, (size_t)out_size * sizeof(float), stream);
    vl_main<<<dim3(256), dim3(512), 0, stream>>>(x, muw, rhow, epsw,
                                                 mub, rhob, epsb, out);
}